// Round 8
// baseline (1444.105 us; speedup 1.0000x reference)
//
#include <hip/hip_runtime.h>
#include <hip/hip_bf16.h>
#include <math.h>

#define HID 256
#define BSZ 64
#define TLEN 256
#define INW 64
#define OUTW 32
#define NOISE_STD 0.05f
#define TAU 0.2f

typedef __attribute__((ext_vector_type(8))) short short8;
typedef __attribute__((ext_vector_type(4))) short shortx4;
typedef __attribute__((ext_vector_type(4))) float floatx4;
typedef unsigned long long u64;

// LDS layout for r: [b][k], 8-short-granule XOR swizzle (R0-proven).
__device__ __forceinline__ int ridx(int b, int k) {
    int P = ((b >> 2) & 7) ^ ((b & 3) << 1);
    return b * 256 + ((((k >> 3) ^ P) & 31) << 3) + (k & 7);
}

// fast tanh: 1 - 2/(e^{2x}+1). Saturates correctly; |err| << bf16 quantum.
__device__ __forceinline__ float fast_tanh(float x) {
    float e = __expf(2.f * x);
    return 1.f - 2.f / (e + 1.f);
}

// ---------------------------------------------------------------------------
// one-time: W [j][i][k] fp32 -> bf16 in MFMA B-fragment order
// ---------------------------------------------------------------------------
__global__ __launch_bounds__(256) void swizzle_kernel(const float* __restrict__ W,
                                                      __hip_bfloat16* __restrict__ Wsw) {
    int g = blockIdx.x * 256 + threadIdx.x;      // 0 .. 2^21-1
    int l  = g & 63;
    int ni = (g >> 6) & 15;
    int kk = (g >> 10) & 7;
    int j  = g >> 13;
    int i  = ni * 16 + (l & 15);
    int k0 = kk * 32 + (l >> 4) * 8;
    const float* __restrict__ src = W + ((size_t)j * HID + i) * HID + k0;
    __hip_bfloat16* __restrict__ dst = Wsw + (size_t)g * 8;
#pragma unroll
    for (int e = 0; e < 8; ++e) dst[e] = __float2bfloat16(src[e]);
}

// ---------------------------------------------------------------------------
// init: buf0[g*256+k] = pack4(bf16(tanh(x0[4g+e][k])))   (transposed packets)
// ---------------------------------------------------------------------------
__global__ __launch_bounds__(256) void init_kernel(const float* __restrict__ x0,
                                                   u64* __restrict__ buf0) {
    int g = blockIdx.x;          // 0..15
    int k = threadIdx.x;
    u64 v = 0;
#pragma unroll
    for (int e = 0; e < 4; ++e) {
        __hip_bfloat16 h = __float2bfloat16(tanhf(x0[(4 * g + e) * HID + k]));
        v |= (u64)(*(unsigned short*)&h) << (16 * e);
    }
    buf0[g * 256 + k] = v;
}

// ---------------------------------------------------------------------------
// one-time: pre[t][j][b] = NOISE_STD*noise[t][b][j]
//                        + TAU*(w_in_b[j] + sum_in u[b][t][in]*w_in_w[j][in])
// ---------------------------------------------------------------------------
__global__ __launch_bounds__(256) void pre_kernel(const float* __restrict__ u,
                                                  const float* __restrict__ w_in_w,
                                                  const float* __restrict__ w_in_b,
                                                  const float* __restrict__ noise,
                                                  float* __restrict__ pre) {
    __shared__ float ulds[BSZ][INW + 4];
    const int t = blockIdx.x;
    const int j = threadIdx.x;
    {
        int b = threadIdx.x >> 2, q = threadIdx.x & 3;
#pragma unroll
        for (int e = 0; e < 4; ++e) {
            float4 v = *(const float4*)(u + ((size_t)b * TLEN + t) * INW + q * 16 + e * 4);
            *(float4*)&ulds[b][q * 16 + e * 4] = v;
        }
    }
    float wreg[INW];
#pragma unroll
    for (int q = 0; q < INW / 4; ++q) {
        float4 v = *(const float4*)(w_in_w + (size_t)j * INW + q * 4);
        wreg[q * 4 + 0] = v.x; wreg[q * 4 + 1] = v.y;
        wreg[q * 4 + 2] = v.z; wreg[q * 4 + 3] = v.w;
    }
    float bias = w_in_b[j];
    __syncthreads();
    for (int b = 0; b < BSZ; ++b) {
        float s = bias;
#pragma unroll
        for (int in_ = 0; in_ < INW; ++in_) s = fmaf(ulds[b][in_], wreg[in_], s);
        float nz = noise[((size_t)t * BSZ + b) * HID + j];
        pre[((size_t)t * HID + j) * BSZ + b] = NOISE_STD * nz + TAU * s;
    }
}

// ---------------------------------------------------------------------------
// persistent kernel — R7 structure (protocol FROZEN) + split ack-chains:
//  - waves 0 AND 1 both compute xn (bit-identical: same code path; wave1
//    gets `extra` via exl[] LDS handoff written pre-barrier-B, read
//    post-barrier-B so its latency hides under the GEMM)
//  - wave1 = publisher (tanh/pack/publish/drain/flag), wave0 = trajWS only.
//    The flag-ack and trajWS-ack chains run in PARALLEL on different waves
//    (previously serialized on wave0, delaying its next-step poll).
//  - both waves drain vmcnt(0) post-store: the ack-wait overlaps the
//    remote-flag window instead of the poll path.
// ---------------------------------------------------------------------------
__global__ __launch_bounds__(256, 1) void persist_kernel(
    const __hip_bfloat16* __restrict__ Wsw,
    const float* __restrict__ w_hh,
    const float* __restrict__ u,              // fallbacks
    const float* __restrict__ w_in_w,
    const float* __restrict__ w_in_b,
    const float* __restrict__ noise,
    const float* __restrict__ x0,
    u64* __restrict__ buf0,                   // [16][256] packets (t even reads)
    u64* __restrict__ buf1,                   // (t odd reads)
    float* __restrict__ traj,                 // [B][T][HID] (fallback path)
    float* __restrict__ trajWS,               // [T][HID][B] (fast path)
    float* __restrict__ xfinal,
    int* __restrict__ ready,                  // 256 flags, 64B apart (zeroed)
    const float* __restrict__ pre,            // [T][HID][B] or unused
    int use_pre, int use_tws) {
    __shared__ short rlds[16384];             // 32 KB swizzled r
    __shared__ float redw[256];               // [b][w] transposed partials
    __shared__ float exl[2][64];              // extra handoff wave0 -> wave1

    const int tid  = threadIdx.x;
    const int j    = blockIdx.x;
    const int w    = tid >> 6;
    const int lane = tid & 63;
    const int quad = lane >> 4;
    const int col  = lane & 15;

    // ---- W fragments into registers: 32 x short8 = 128 VGPRs (swapped-MFMA
    //      A-operand; A/B frag layouts identical) ----
    short8 wreg[32];
    {
        const short* __restrict__ wsh = (const short*)Wsw;
#pragma unroll
        for (int kk = 0; kk < 8; ++kk)
#pragma unroll
            for (int mt = 0; mt < 4; ++mt)
                wreg[kk * 4 + mt] = *(const short8*)(wsh +
                    ((((size_t)j * 8 + kk) * 16 + (w * 4 + mt)) * 64 + lane) * 8);
    }
    // whh folded into MFMA acc init (verified R5/R6/R7)
    float whh16[16];
#pragma unroll
    for (int mt = 0; mt < 4; ++mt)
#pragma unroll
        for (int rg = 0; rg < 4; ++rg)
            whh16[mt * 4 + rg] = w_hh[j * HID + (w * 4 + mt) * 16 + quad * 4 + rg];

    // state copy in waves 0 AND 1 (identical arithmetic keeps them in sync)
    float xb = 0.f;
    if (tid < 128) xb = x0[lane * HID + j];

#pragma unroll 1
    for (int t = 0; t < TLEN; ++t) {
        const u64* __restrict__ rcur = (t & 1) ? buf1 : buf0;
        u64* __restrict__ rnxt = (t & 1) ? buf0 : buf1;

        // ---- input term (wave0 only) + LDS handoff for wave1 ----
        float extra = 0.f;
        if (tid < BSZ) {
            if (use_pre) {
                extra = pre[((size_t)t * HID + j) * BSZ + tid];
            } else {
                float isum = w_in_b[j];
                const float4* __restrict__ urow =
                    (const float4*)(u + ((size_t)tid * TLEN + t) * INW);
                const float4* __restrict__ wrow = (const float4*)(w_in_w + (size_t)j * INW);
#pragma unroll
                for (int q = 0; q < INW / 4; ++q) {
                    float4 uu = urow[q], ww = wrow[q];
                    isum = fmaf(uu.x, ww.x, isum);
                    isum = fmaf(uu.y, ww.y, isum);
                    isum = fmaf(uu.z, ww.z, isum);
                    isum = fmaf(uu.w, ww.w, isum);
                }
                float nz = noise[((size_t)t * BSZ + tid) * HID + j];
                extra = NOISE_STD * nz + TAU * isum;
            }
            exl[t & 1][tid] = extra;           // visible to wave1 after barrier B
        }

        // ---- thread-local wait: flag tid guards exactly this thread's data ----
        if (t > 0) {
            while (__hip_atomic_load(ready + tid * 16, __ATOMIC_RELAXED,
                                     __HIP_MEMORY_SCOPE_AGENT) < t)
                __builtin_amdgcn_s_sleep(1);
            asm volatile("" ::: "memory");
        }

        // ---- load own column (producer tid's output), fill rlds ----
        {
            u64 v[16];
#pragma unroll
            for (int g = 0; g < 16; ++g)
                v[g] = __hip_atomic_load(rcur + g * 256 + tid, __ATOMIC_RELAXED,
                                         __HIP_MEMORY_SCOPE_AGENT);
#pragma unroll
            for (int g = 0; g < 16; ++g)
#pragma unroll
                for (int e = 0; e < 4; ++e)
                    rlds[ridx(4 * g + e, tid)] = (short)(v[g] >> (16 * e));
        }
        __syncthreads();                       // barrier B: rlds (+exl) complete

        // wave1's extra, read early so the ds_read hides under the GEMM
        float ex_w1 = 0.f;
        if (w == 1) ex_w1 = exl[t & 1][lane];

        // ---- GEMM (swapped): D[i,b] = w_hh[j,i] + sum_k W[j,i,k] r[b,k] ----
        floatx4 acc[4][4];                     // acc[mt=i-tile][nt=b-tile]
#pragma unroll
        for (int mt = 0; mt < 4; ++mt)
#pragma unroll
            for (int nt = 0; nt < 4; ++nt)
                acc[mt][nt] = (floatx4){whh16[mt * 4 + 0], whh16[mt * 4 + 1],
                                        whh16[mt * 4 + 2], whh16[mt * 4 + 3]};

#pragma unroll
        for (int kk = 0; kk < 8; ++kk) {
            short8 afrag[4];
#pragma unroll
            for (int nt = 0; nt < 4; ++nt)
                afrag[nt] = *(const short8*)&rlds[ridx(nt * 16 + col, kk * 32 + quad * 8)];
#pragma unroll
            for (int mt = 0; mt < 4; ++mt)
#pragma unroll
                for (int nt = 0; nt < 4; ++nt)
                    acc[mt][nt] = __builtin_amdgcn_mfma_f32_16x16x32_bf16(
                        wreg[kk * 4 + mt], afrag[nt], acc[mt][nt], 0, 0, 0);
        }

        // ---- epilogue: part[b] = sum_i r[b,i]*P'[i,b] ----
        float part[4];
#pragma unroll
        for (int nt = 0; nt < 4; ++nt) part[nt] = 0.f;
#pragma unroll
        for (int mt = 0; mt < 4; ++mt) {
            const int ib = (w * 4 + mt) * 16 + quad * 4;
#pragma unroll
            for (int nt = 0; nt < 4; ++nt) {
                const int b = nt * 16 + col;
                shortx4 r4 = *(const shortx4*)&rlds[ridx(b, ib)];
#pragma unroll
                for (int rg = 0; rg < 4; ++rg) {
                    short rs = r4[rg];
                    float rv = __bfloat162float(*(__hip_bfloat16*)&rs);
                    part[nt] = fmaf(rv, acc[mt][nt][rg], part[nt]);
                }
            }
        }
#pragma unroll
        for (int nt = 0; nt < 4; ++nt) {
            part[nt] += __shfl_xor(part[nt], 16, 64);
            part[nt] += __shfl_xor(part[nt], 32, 64);
        }
        // transposed partial store: redw[b*4 + w] -> one float4 read per b
        if (quad == 0) {
#pragma unroll
            for (int nt = 0; nt < 4; ++nt)
                redw[(nt * 16 + col) * 4 + w] = part[nt];
        }
        __syncthreads();                       // barrier C: redw complete

        // ---- waves 0 & 1: both compute xn (identical); split store duties ----
        if (w < 2) {
            const int b = lane;
            float4 r4 = *(const float4*)&redw[b * 4];      // one ds_read_b128
            float rec = (r4.x + r4.y) + (r4.z + r4.w);
            float ex = (w == 0) ? extra : ex_w1;
            float xn = xb + ex + TAU * (rec - xb);
            xb = xn;

            if (w == 1) {
                // -------- publisher wave --------
                if (t < TLEN - 1) {
                    __hip_bfloat16 h = __float2bfloat16(fast_tanh(xn));
                    int hs = (int)(*(unsigned short*)&h);
                    int src = 4 * (lane & 15);
                    u64 pv = (u64)(unsigned)__shfl(hs, src + 0, 64)
                           | ((u64)(unsigned)__shfl(hs, src + 1, 64) << 16)
                           | ((u64)(unsigned)__shfl(hs, src + 2, 64) << 32)
                           | ((u64)(unsigned)__shfl(hs, src + 3, 64) << 48);
                    if (lane < 16)
                        __hip_atomic_store(rnxt + (size_t)lane * 256 + j, pv,
                                           __ATOMIC_RELAXED, __HIP_MEMORY_SCOPE_AGENT);
                    asm volatile("s_waitcnt vmcnt(0)" ::: "memory");   // data drain
                    if (lane == 0)
                        __hip_atomic_store(ready + j * 16, t + 1, __ATOMIC_RELAXED,
                                           __HIP_MEMORY_SCOPE_AGENT);
                    // flag-ack drain here, overlapped with the remote-flag
                    // window (all waves wait on remote producers anyway)
                    asm volatile("s_waitcnt vmcnt(0)" ::: "memory");
                }
            } else {
                // -------- trajectory wave --------
                if (use_tws) {
                    trajWS[((size_t)t * HID + j) * BSZ + b] = xn;      // 256B coalesced
                } else {
                    traj[((size_t)b * TLEN + t) * HID + j] = xn;
                    if (t == TLEN - 1) xfinal[b * HID + j] = xn;
                }
                // store-ack drain off the poll path (overlaps remote window)
                asm volatile("s_waitcnt vmcnt(0)" ::: "memory");
            }
        }
    }
}

// ---------------------------------------------------------------------------
// fused transpose + output (fast path). block = t.
// ---------------------------------------------------------------------------
__global__ __launch_bounds__(256) void fixup_kernel(
    const float* __restrict__ trajWS,   // [T][HID][B]
    const float* __restrict__ w_out_w,  // [OUT][HID]
    const float* __restrict__ w_out_b,  // [OUT]
    float* __restrict__ traj,           // [B][T][HID]
    float* __restrict__ xfinal,         // [B][HID]
    float* __restrict__ out) {          // [B][T][OUT]
    __shared__ float xv[BSZ * 257];
    __shared__ float wol[OUTW * 257];
    const int t = blockIdx.x, tid = threadIdx.x;

#pragma unroll
    for (int it = 0; it < 16; ++it) {
        int flat = it * 1024 + tid * 4;          // j*64 + b
        float4 v = *(const float4*)(trajWS + (size_t)t * 16384 + flat);
        int jj = flat >> 6, b = flat & 63;
        xv[(b + 0) * 257 + jj] = v.x;
        xv[(b + 1) * 257 + jj] = v.y;
        xv[(b + 2) * 257 + jj] = v.z;
        xv[(b + 3) * 257 + jj] = v.w;
    }
#pragma unroll
    for (int it = 0; it < 8; ++it) {
        int flat = it * 1024 + tid * 4;          // o*256 + h
        float4 v = *(const float4*)(w_out_w + flat);
        int o = flat >> 8, h = flat & 255;
        *(float4*)&wol[o * 257 + h] = v;
    }
    __syncthreads();

    for (int b = 0; b < BSZ; ++b)
        traj[((size_t)b * TLEN + t) * HID + tid] = xv[b * 257 + tid];
    if (t == TLEN - 1)
        for (int b = 0; b < BSZ; ++b)
            xfinal[b * HID + tid] = xv[b * 257 + tid];

    __syncthreads();
#pragma unroll
    for (int it = 0; it < 64; ++it)
        xv[it * 257 + tid] = tanhf(xv[it * 257 + tid]);
    __syncthreads();

    const int o = tid & 31;
    const float bias = w_out_b[o];
#pragma unroll 1
    for (int rep = 0; rep < 8; ++rep) {
        int b = rep * 8 + (tid >> 5);
        float s = bias;
#pragma unroll 8
        for (int h = 0; h < HID; ++h)
            s = fmaf(xv[b * 257 + h], wol[o * 257 + h], s);
        out[((size_t)b * TLEN + t) * OUTW + o] = s;
    }
}

// ---------------------------------------------------------------------------
// fallback output kernel — used when ws too small
// ---------------------------------------------------------------------------
__global__ __launch_bounds__(256) void output_kernel(
    const float* __restrict__ traj, const float* __restrict__ w_out_w,
    const float* __restrict__ w_out_b, float* __restrict__ out) {
    __shared__ float th[8][HID + 1];
    const int bt0 = blockIdx.x * 8;
    const int tid = threadIdx.x;
#pragma unroll
    for (int m = 0; m < 8; ++m) {
        int idx = m * 256 + tid;
        th[idx >> 8][idx & 255] = tanhf(traj[(size_t)bt0 * HID + idx]);
    }
    __syncthreads();
    const int row = tid >> 5, o = tid & 31;
    const float* __restrict__ wrow = w_out_w + (size_t)o * HID;
    float s = w_out_b[o];
#pragma unroll 8
    for (int h = 0; h < HID; ++h) s = fmaf(th[row][h], wrow[h], s);
    out[(size_t)(bt0 + row) * OUTW + o] = s;
}

// ---------------------------------------------------------------------------
extern "C" void kernel_launch(void* const* d_in, const int* in_sizes, int n_in,
                              void* d_out, int out_size, void* d_ws, size_t ws_size,
                              hipStream_t stream) {
    const float* u       = (const float*)d_in[0];
    const float* x0      = (const float*)d_in[1];
    const float* noise   = (const float*)d_in[2];
    const float* w_hh    = (const float*)d_in[3];
    const float* W       = (const float*)d_in[4];
    const float* w_in_w  = (const float*)d_in[5];
    const float* w_in_b  = (const float*)d_in[6];
    const float* w_out_w = (const float*)d_in[7];
    const float* w_out_b = (const float*)d_in[8];

    float* out    = (float*)d_out;                     // [B][T][OUT]
    float* xfinal = out + (size_t)BSZ * TLEN * OUTW;
    float* traj   = xfinal + (size_t)BSZ * HID;

    // ws layout: Wsw 33.5M | buf0 32K | buf1 32K | flags 16K | trajWS 16.7M | pre 16.7M
    char* ws = (char*)d_ws;
    __hip_bfloat16* Wsw = (__hip_bfloat16*)ws;
    u64*   buf0 = (u64*)(ws + 33554432);
    u64*   buf1 = (u64*)(ws + 33587200);
    int*   rdy  = (int*)(ws + 33619968);
    float* tws  = (float*)(ws + 33636352);
    float* pre  = (float*)(ws + 50413568);
    const size_t NEED_TWS = 50413568ull;
    const size_t NEED_PRE = 67190784ull;
    const int use_tws = (ws_size >= NEED_TWS) ? 1 : 0;
    const int use_pre = (ws_size >= NEED_PRE) ? 1 : 0;

    hipMemsetAsync(rdy, 0, 16384, stream);
    swizzle_kernel<<<8192, 256, 0, stream>>>(W, Wsw);
    init_kernel<<<16, 256, 0, stream>>>(x0, buf0);
    if (use_pre)
        pre_kernel<<<TLEN, 256, 0, stream>>>(u, w_in_w, w_in_b, noise, pre);

    persist_kernel<<<256, 256, 0, stream>>>(
        Wsw, w_hh, u, w_in_w, w_in_b, noise, x0,
        buf0, buf1, traj, tws, xfinal, rdy, pre, use_pre, use_tws);

    if (use_tws)
        fixup_kernel<<<TLEN, 256, 0, stream>>>(tws, w_out_w, w_out_b, traj, xfinal, out);
    else
        output_kernel<<<(BSZ * TLEN) / 8, 256, 0, stream>>>(traj, w_out_w, w_out_b, out);
}

// Round 9
// 1439.306 us; speedup vs baseline: 1.0033x; 1.0033x over previous
//
#include <hip/hip_runtime.h>
#include <hip/hip_bf16.h>
#include <math.h>

#define HID 256
#define BSZ 64
#define TLEN 256
#define INW 64
#define OUTW 32
#define NOISE_STD 0.05f
#define TAU 0.2f

typedef __attribute__((ext_vector_type(8))) short short8;
typedef __attribute__((ext_vector_type(4))) short shortx4;
typedef __attribute__((ext_vector_type(4))) float floatx4;
typedef unsigned long long u64;

// LDS layout for r: [b][k], 8-short-granule XOR swizzle (R0-proven).
__device__ __forceinline__ int ridx(int b, int k) {
    int P = ((b >> 2) & 7) ^ ((b & 3) << 1);
    return b * 256 + ((((k >> 3) ^ P) & 31) << 3) + (k & 7);
}

// fast tanh: 1 - 2/(e^{2x}+1). Saturates correctly; |err| << bf16 quantum.
__device__ __forceinline__ float fast_tanh(float x) {
    float e = __expf(2.f * x);
    return 1.f - 2.f / (e + 1.f);
}

// ---------------------------------------------------------------------------
// init: buf0[g*256+k] = pack4(bf16(tanh(x0[4g+e][k])))   (transposed packets)
// standalone form used only on the no-pre fallback path
// ---------------------------------------------------------------------------
__device__ __forceinline__ void init_body(const float* __restrict__ x0,
                                          u64* __restrict__ buf0, int g, int k) {
    u64 v = 0;
#pragma unroll
    for (int e = 0; e < 4; ++e) {
        __hip_bfloat16 h = __float2bfloat16(tanhf(x0[(4 * g + e) * HID + k]));
        v |= (u64)(*(unsigned short*)&h) << (16 * e);
    }
    buf0[g * 256 + k] = v;
}

__global__ __launch_bounds__(256) void init_kernel(const float* __restrict__ x0,
                                                   u64* __restrict__ buf0) {
    init_body(x0, buf0, blockIdx.x, threadIdx.x);
}

// ---------------------------------------------------------------------------
// one-time: pre[t][j][b] = NOISE_STD*noise[t][b][j]
//                        + TAU*(w_in_b[j] + sum_in u[b][t][in]*w_in_w[j][in])
// blocks 0..15 additionally perform the init duty (one fewer dispatch)
// ---------------------------------------------------------------------------
__global__ __launch_bounds__(256) void pre_kernel(const float* __restrict__ u,
                                                  const float* __restrict__ w_in_w,
                                                  const float* __restrict__ w_in_b,
                                                  const float* __restrict__ noise,
                                                  float* __restrict__ pre,
                                                  const float* __restrict__ x0,
                                                  u64* __restrict__ buf0) {
    __shared__ float ulds[BSZ][INW + 4];
    const int t = blockIdx.x;
    const int j = threadIdx.x;
    if (t < 16) init_body(x0, buf0, t, j);    // fused init (blocks 0..15)
    {
        int b = threadIdx.x >> 2, q = threadIdx.x & 3;
#pragma unroll
        for (int e = 0; e < 4; ++e) {
            float4 v = *(const float4*)(u + ((size_t)b * TLEN + t) * INW + q * 16 + e * 4);
            *(float4*)&ulds[b][q * 16 + e * 4] = v;
        }
    }
    float wreg[INW];
#pragma unroll
    for (int q = 0; q < INW / 4; ++q) {
        float4 v = *(const float4*)(w_in_w + (size_t)j * INW + q * 4);
        wreg[q * 4 + 0] = v.x; wreg[q * 4 + 1] = v.y;
        wreg[q * 4 + 2] = v.z; wreg[q * 4 + 3] = v.w;
    }
    float bias = w_in_b[j];
    __syncthreads();
    for (int b = 0; b < BSZ; ++b) {
        float s = bias;
#pragma unroll
        for (int in_ = 0; in_ < INW; ++in_) s = fmaf(ulds[b][in_], wreg[in_], s);
        float nz = noise[((size_t)t * BSZ + b) * HID + j];
        pre[((size_t)t * HID + j) * BSZ + b] = NOISE_STD * nz + TAU * s;
    }
}

// ---------------------------------------------------------------------------
// persistent kernel — R8 structure (protocol + step loop FROZEN at the
// fabric-latency floor) + swizzle folded into the prologue:
//  - W fragments loaded DIRECTLY from W[j] (fp32->bf16 in-register). Per
//    (kk,mt) the 64 lanes cover a full 16x32 fp32 tile -> 100% line
//    utilization. Eliminates the swizzle kernel + 67MB of Wsw round-trip.
//  - waves 0 & 1 dual-compute xn; wave1 publishes (pack/stores/drain/flag),
//    wave0 stores trajWS; ack-chains in parallel (R8).
//  - w_hh folded into MFMA acc init; transposed redw; fast_tanh (R7).
// ---------------------------------------------------------------------------
__global__ __launch_bounds__(256, 1) void persist_kernel(
    const float* __restrict__ W,              // [HID][HID][HID] fp32
    const float* __restrict__ w_hh,
    const float* __restrict__ u,              // fallbacks
    const float* __restrict__ w_in_w,
    const float* __restrict__ w_in_b,
    const float* __restrict__ noise,
    const float* __restrict__ x0,
    u64* __restrict__ buf0,                   // [16][256] packets (t even reads)
    u64* __restrict__ buf1,                   // (t odd reads)
    float* __restrict__ traj,                 // [B][T][HID] (fallback path)
    float* __restrict__ trajWS,               // [T][HID][B] (fast path)
    float* __restrict__ xfinal,
    int* __restrict__ ready,                  // 256 flags, 64B apart (zeroed)
    const float* __restrict__ pre,            // [T][HID][B] or unused
    int use_pre, int use_tws) {
    __shared__ short rlds[16384];             // 32 KB swizzled r
    __shared__ float redw[256];               // [b][w] transposed partials
    __shared__ float exl[2][64];              // extra handoff wave0 -> wave1

    const int tid  = threadIdx.x;
    const int j    = blockIdx.x;
    const int w    = tid >> 6;
    const int lane = tid & 63;
    const int quad = lane >> 4;
    const int col  = lane & 15;

    // ---- W fragments direct from W: wreg[kk*4+mt][e] =
    //      bf16(W[j][(w*4+mt)*16+col][kk*32+quad*8+e])  (swapped-MFMA A-op)
    short8 wreg[32];
    {
        const float* __restrict__ wsrc = W + (size_t)j * HID * HID;
#pragma unroll
        for (int kk = 0; kk < 8; ++kk)
#pragma unroll
            for (int mt = 0; mt < 4; ++mt) {
                const float* __restrict__ p =
                    wsrc + (size_t)((w * 4 + mt) * 16 + col) * HID + kk * 32 + quad * 8;
                float4 f0 = *(const float4*)p;
                float4 f1 = *(const float4*)(p + 4);
                short8 s;
                __hip_bfloat16 h;
                h = __float2bfloat16(f0.x); s[0] = *(short*)&h;
                h = __float2bfloat16(f0.y); s[1] = *(short*)&h;
                h = __float2bfloat16(f0.z); s[2] = *(short*)&h;
                h = __float2bfloat16(f0.w); s[3] = *(short*)&h;
                h = __float2bfloat16(f1.x); s[4] = *(short*)&h;
                h = __float2bfloat16(f1.y); s[5] = *(short*)&h;
                h = __float2bfloat16(f1.z); s[6] = *(short*)&h;
                h = __float2bfloat16(f1.w); s[7] = *(short*)&h;
                wreg[kk * 4 + mt] = s;
            }
    }
    // whh folded into MFMA acc init (verified R5-R8)
    float whh16[16];
#pragma unroll
    for (int mt = 0; mt < 4; ++mt)
#pragma unroll
        for (int rg = 0; rg < 4; ++rg)
            whh16[mt * 4 + rg] = w_hh[j * HID + (w * 4 + mt) * 16 + quad * 4 + rg];

    // state copy in waves 0 AND 1 (identical arithmetic keeps them in sync)
    float xb = 0.f;
    if (tid < 128) xb = x0[lane * HID + j];

#pragma unroll 1
    for (int t = 0; t < TLEN; ++t) {
        const u64* __restrict__ rcur = (t & 1) ? buf1 : buf0;
        u64* __restrict__ rnxt = (t & 1) ? buf0 : buf1;

        // ---- input term (wave0 only) + LDS handoff for wave1 ----
        float extra = 0.f;
        if (tid < BSZ) {
            if (use_pre) {
                extra = pre[((size_t)t * HID + j) * BSZ + tid];
            } else {
                float isum = w_in_b[j];
                const float4* __restrict__ urow =
                    (const float4*)(u + ((size_t)tid * TLEN + t) * INW);
                const float4* __restrict__ wrow = (const float4*)(w_in_w + (size_t)j * INW);
#pragma unroll
                for (int q = 0; q < INW / 4; ++q) {
                    float4 uu = urow[q], ww = wrow[q];
                    isum = fmaf(uu.x, ww.x, isum);
                    isum = fmaf(uu.y, ww.y, isum);
                    isum = fmaf(uu.z, ww.z, isum);
                    isum = fmaf(uu.w, ww.w, isum);
                }
                float nz = noise[((size_t)t * BSZ + tid) * HID + j];
                extra = NOISE_STD * nz + TAU * isum;
            }
            exl[t & 1][tid] = extra;           // visible to wave1 after barrier B
        }

        // ---- thread-local wait: flag tid guards exactly this thread's data ----
        if (t > 0) {
            while (__hip_atomic_load(ready + tid * 16, __ATOMIC_RELAXED,
                                     __HIP_MEMORY_SCOPE_AGENT) < t)
                __builtin_amdgcn_s_sleep(1);
            asm volatile("" ::: "memory");
        }

        // ---- load own column (producer tid's output), fill rlds ----
        {
            u64 v[16];
#pragma unroll
            for (int g = 0; g < 16; ++g)
                v[g] = __hip_atomic_load(rcur + g * 256 + tid, __ATOMIC_RELAXED,
                                         __HIP_MEMORY_SCOPE_AGENT);
#pragma unroll
            for (int g = 0; g < 16; ++g)
#pragma unroll
                for (int e = 0; e < 4; ++e)
                    rlds[ridx(4 * g + e, tid)] = (short)(v[g] >> (16 * e));
        }
        __syncthreads();                       // barrier B: rlds (+exl) complete

        // wave1's extra, read early so the ds_read hides under the GEMM
        float ex_w1 = 0.f;
        if (w == 1) ex_w1 = exl[t & 1][lane];

        // ---- GEMM (swapped): D[i,b] = w_hh[j,i] + sum_k W[j,i,k] r[b,k] ----
        floatx4 acc[4][4];                     // acc[mt=i-tile][nt=b-tile]
#pragma unroll
        for (int mt = 0; mt < 4; ++mt)
#pragma unroll
            for (int nt = 0; nt < 4; ++nt)
                acc[mt][nt] = (floatx4){whh16[mt * 4 + 0], whh16[mt * 4 + 1],
                                        whh16[mt * 4 + 2], whh16[mt * 4 + 3]};

#pragma unroll
        for (int kk = 0; kk < 8; ++kk) {
            short8 afrag[4];
#pragma unroll
            for (int nt = 0; nt < 4; ++nt)
                afrag[nt] = *(const short8*)&rlds[ridx(nt * 16 + col, kk * 32 + quad * 8)];
#pragma unroll
            for (int mt = 0; mt < 4; ++mt)
#pragma unroll
                for (int nt = 0; nt < 4; ++nt)
                    acc[mt][nt] = __builtin_amdgcn_mfma_f32_16x16x32_bf16(
                        wreg[kk * 4 + mt], afrag[nt], acc[mt][nt], 0, 0, 0);
        }

        // ---- epilogue: part[b] = sum_i r[b,i]*P'[i,b] ----
        float part[4];
#pragma unroll
        for (int nt = 0; nt < 4; ++nt) part[nt] = 0.f;
#pragma unroll
        for (int mt = 0; mt < 4; ++mt) {
            const int ib = (w * 4 + mt) * 16 + quad * 4;
#pragma unroll
            for (int nt = 0; nt < 4; ++nt) {
                const int b = nt * 16 + col;
                shortx4 r4 = *(const shortx4*)&rlds[ridx(b, ib)];
#pragma unroll
                for (int rg = 0; rg < 4; ++rg) {
                    short rs = r4[rg];
                    float rv = __bfloat162float(*(__hip_bfloat16*)&rs);
                    part[nt] = fmaf(rv, acc[mt][nt][rg], part[nt]);
                }
            }
        }
#pragma unroll
        for (int nt = 0; nt < 4; ++nt) {
            part[nt] += __shfl_xor(part[nt], 16, 64);
            part[nt] += __shfl_xor(part[nt], 32, 64);
        }
        // transposed partial store: redw[b*4 + w] -> one float4 read per b
        if (quad == 0) {
#pragma unroll
            for (int nt = 0; nt < 4; ++nt)
                redw[(nt * 16 + col) * 4 + w] = part[nt];
        }
        __syncthreads();                       // barrier C: redw complete

        // ---- waves 0 & 1: both compute xn (identical); split store duties ----
        if (w < 2) {
            const int b = lane;
            float4 r4 = *(const float4*)&redw[b * 4];      // one ds_read_b128
            float rec = (r4.x + r4.y) + (r4.z + r4.w);
            float ex = (w == 0) ? extra : ex_w1;
            float xn = xb + ex + TAU * (rec - xb);
            xb = xn;

            if (w == 1) {
                // -------- publisher wave --------
                if (t < TLEN - 1) {
                    __hip_bfloat16 h = __float2bfloat16(fast_tanh(xn));
                    int hs = (int)(*(unsigned short*)&h);
                    int src = 4 * (lane & 15);
                    u64 pv = (u64)(unsigned)__shfl(hs, src + 0, 64)
                           | ((u64)(unsigned)__shfl(hs, src + 1, 64) << 16)
                           | ((u64)(unsigned)__shfl(hs, src + 2, 64) << 32)
                           | ((u64)(unsigned)__shfl(hs, src + 3, 64) << 48);
                    if (lane < 16)
                        __hip_atomic_store(rnxt + (size_t)lane * 256 + j, pv,
                                           __ATOMIC_RELAXED, __HIP_MEMORY_SCOPE_AGENT);
                    asm volatile("s_waitcnt vmcnt(0)" ::: "memory");   // data drain
                    if (lane == 0)
                        __hip_atomic_store(ready + j * 16, t + 1, __ATOMIC_RELAXED,
                                           __HIP_MEMORY_SCOPE_AGENT);
                    // flag-ack drain overlapped with the remote-flag window
                    asm volatile("s_waitcnt vmcnt(0)" ::: "memory");
                }
            } else {
                // -------- trajectory wave --------
                if (use_tws) {
                    trajWS[((size_t)t * HID + j) * BSZ + b] = xn;      // 256B coalesced
                } else {
                    traj[((size_t)b * TLEN + t) * HID + j] = xn;
                    if (t == TLEN - 1) xfinal[b * HID + j] = xn;
                }
                // store-ack drain off the poll path (overlaps remote window)
                asm volatile("s_waitcnt vmcnt(0)" ::: "memory");
            }
        }
    }
}

// ---------------------------------------------------------------------------
// fused transpose + output (fast path). block = t.
// ---------------------------------------------------------------------------
__global__ __launch_bounds__(256) void fixup_kernel(
    const float* __restrict__ trajWS,   // [T][HID][B]
    const float* __restrict__ w_out_w,  // [OUT][HID]
    const float* __restrict__ w_out_b,  // [OUT]
    float* __restrict__ traj,           // [B][T][HID]
    float* __restrict__ xfinal,         // [B][HID]
    float* __restrict__ out) {          // [B][T][OUT]
    __shared__ float xv[BSZ * 257];
    __shared__ float wol[OUTW * 257];
    const int t = blockIdx.x, tid = threadIdx.x;

#pragma unroll
    for (int it = 0; it < 16; ++it) {
        int flat = it * 1024 + tid * 4;          // j*64 + b
        float4 v = *(const float4*)(trajWS + (size_t)t * 16384 + flat);
        int jj = flat >> 6, b = flat & 63;
        xv[(b + 0) * 257 + jj] = v.x;
        xv[(b + 1) * 257 + jj] = v.y;
        xv[(b + 2) * 257 + jj] = v.z;
        xv[(b + 3) * 257 + jj] = v.w;
    }
#pragma unroll
    for (int it = 0; it < 8; ++it) {
        int flat = it * 1024 + tid * 4;          // o*256 + h
        float4 v = *(const float4*)(w_out_w + flat);
        int o = flat >> 8, h = flat & 255;
        *(float4*)&wol[o * 257 + h] = v;
    }
    __syncthreads();

    for (int b = 0; b < BSZ; ++b)
        traj[((size_t)b * TLEN + t) * HID + tid] = xv[b * 257 + tid];
    if (t == TLEN - 1)
        for (int b = 0; b < BSZ; ++b)
            xfinal[b * HID + tid] = xv[b * 257 + tid];

    __syncthreads();
#pragma unroll
    for (int it = 0; it < 64; ++it)
        xv[it * 257 + tid] = tanhf(xv[it * 257 + tid]);
    __syncthreads();

    const int o = tid & 31;
    const float bias = w_out_b[o];
#pragma unroll 1
    for (int rep = 0; rep < 8; ++rep) {
        int b = rep * 8 + (tid >> 5);
        float s = bias;
#pragma unroll 8
        for (int h = 0; h < HID; ++h)
            s = fmaf(xv[b * 257 + h], wol[o * 257 + h], s);
        out[((size_t)b * TLEN + t) * OUTW + o] = s;
    }
}

// ---------------------------------------------------------------------------
// fallback output kernel — used when ws too small
// ---------------------------------------------------------------------------
__global__ __launch_bounds__(256) void output_kernel(
    const float* __restrict__ traj, const float* __restrict__ w_out_w,
    const float* __restrict__ w_out_b, float* __restrict__ out) {
    __shared__ float th[8][HID + 1];
    const int bt0 = blockIdx.x * 8;
    const int tid = threadIdx.x;
#pragma unroll
    for (int m = 0; m < 8; ++m) {
        int idx = m * 256 + tid;
        th[idx >> 8][idx & 255] = tanhf(traj[(size_t)bt0 * HID + idx]);
    }
    __syncthreads();
    const int row = tid >> 5, o = tid & 31;
    const float* __restrict__ wrow = w_out_w + (size_t)o * HID;
    float s = w_out_b[o];
#pragma unroll 8
    for (int h = 0; h < HID; ++h) s = fmaf(th[row][h], wrow[h], s);
    out[(size_t)(bt0 + row) * OUTW + o] = s;
}

// ---------------------------------------------------------------------------
extern "C" void kernel_launch(void* const* d_in, const int* in_sizes, int n_in,
                              void* d_out, int out_size, void* d_ws, size_t ws_size,
                              hipStream_t stream) {
    const float* u       = (const float*)d_in[0];
    const float* x0      = (const float*)d_in[1];
    const float* noise   = (const float*)d_in[2];
    const float* w_hh    = (const float*)d_in[3];
    const float* W       = (const float*)d_in[4];
    const float* w_in_w  = (const float*)d_in[5];
    const float* w_in_b  = (const float*)d_in[6];
    const float* w_out_w = (const float*)d_in[7];
    const float* w_out_b = (const float*)d_in[8];

    float* out    = (float*)d_out;                     // [B][T][OUT]
    float* xfinal = out + (size_t)BSZ * TLEN * OUTW;
    float* traj   = xfinal + (size_t)BSZ * HID;

    // ws layout (Wsw eliminated): buf0 32K | buf1 32K | flags 16K
    //                            | trajWS 16.7M | pre 16.7M
    char* ws = (char*)d_ws;
    u64*   buf0 = (u64*)ws;
    u64*   buf1 = (u64*)(ws + 32768);
    int*   rdy  = (int*)(ws + 65536);
    float* tws  = (float*)(ws + 81920);
    float* pre  = (float*)(ws + 16859136);
    const size_t NEED_TWS = 16859136ull;
    const size_t NEED_PRE = 33636352ull;
    const int use_tws = (ws_size >= NEED_TWS) ? 1 : 0;
    const int use_pre = (ws_size >= NEED_PRE) ? 1 : 0;

    hipMemsetAsync(rdy, 0, 16384, stream);
    if (use_pre)
        pre_kernel<<<TLEN, 256, 0, stream>>>(u, w_in_w, w_in_b, noise, pre, x0, buf0);
    else
        init_kernel<<<16, 256, 0, stream>>>(x0, buf0);

    persist_kernel<<<256, 256, 0, stream>>>(
        W, w_hh, u, w_in_w, w_in_b, noise, x0,
        buf0, buf1, traj, tws, xfinal, rdy, pre, use_pre, use_tws);

    if (use_tws)
        fixup_kernel<<<TLEN, 256, 0, stream>>>(tws, w_out_w, w_out_b, traj, xfinal, out);
    else
        output_kernel<<<(BSZ * TLEN) / 8, 256, 0, stream>>>(traj, w_out_w, w_out_b, out);
}

// Round 10
// 1430.285 us; speedup vs baseline: 1.0097x; 1.0063x over previous
//
#include <hip/hip_runtime.h>
#include <hip/hip_bf16.h>
#include <math.h>

#define HID 256
#define BSZ 64
#define TLEN 256
#define INW 64
#define OUTW 32
#define NOISE_STD 0.05f
#define TAU 0.2f

typedef __attribute__((ext_vector_type(8))) short short8;
typedef __attribute__((ext_vector_type(4))) short shortx4;
typedef __attribute__((ext_vector_type(4))) float floatx4;
typedef unsigned long long u64;

// LDS layout for r: [b][k], 8-short-granule XOR swizzle (R0-proven).
__device__ __forceinline__ int ridx(int b, int k) {
    int P = ((b >> 2) & 7) ^ ((b & 3) << 1);
    return b * 256 + ((((k >> 3) ^ P) & 31) << 3) + (k & 7);
}

// fast tanh: 1 - 2/(e^{2x}+1). Saturates correctly; |err| << bf16 quantum.
__device__ __forceinline__ float fast_tanh(float x) {
    float e = __expf(2.f * x);
    return 1.f - 2.f / (e + 1.f);
}

// ---------------------------------------------------------------------------
// init: buf0[g*256+k] = pack4(bf16(tanh(x0[4g+e][k])))   (transposed packets)
// ---------------------------------------------------------------------------
__device__ __forceinline__ void init_body(const float* __restrict__ x0,
                                          u64* __restrict__ buf0, int g, int k) {
    u64 v = 0;
#pragma unroll
    for (int e = 0; e < 4; ++e) {
        __hip_bfloat16 h = __float2bfloat16(fast_tanh(x0[(4 * g + e) * HID + k]));
        v |= (u64)(*(unsigned short*)&h) << (16 * e);
    }
    buf0[g * 256 + k] = v;
}

__global__ __launch_bounds__(256) void init_kernel(const float* __restrict__ x0,
                                                   u64* __restrict__ buf0,
                                                   int* __restrict__ rdy) {
    init_body(x0, buf0, blockIdx.x, threadIdx.x);
    rdy[blockIdx.x * 256 + threadIdx.x] = 0;   // 16x256 = 4096 ints = 16KB
}

// ---------------------------------------------------------------------------
// one-time: pre[t][j][b] = NOISE_STD*noise[t][b][j]
//                        + TAU*(w_in_b[j] + sum_in u[b][t][in]*w_in_w[j][in])
// blocks 0..15 additionally do init + flag zeroing (memset dispatch removed)
// ---------------------------------------------------------------------------
__global__ __launch_bounds__(256) void pre_kernel(const float* __restrict__ u,
                                                  const float* __restrict__ w_in_w,
                                                  const float* __restrict__ w_in_b,
                                                  const float* __restrict__ noise,
                                                  float* __restrict__ pre,
                                                  const float* __restrict__ x0,
                                                  u64* __restrict__ buf0,
                                                  int* __restrict__ rdy) {
    __shared__ float ulds[BSZ][INW + 4];
    const int t = blockIdx.x;
    const int j = threadIdx.x;
    if (t < 16) {                              // fused init + flag zeroing
        init_body(x0, buf0, t, j);
        rdy[t * 256 + j] = 0;
    }
    {
        int b = threadIdx.x >> 2, q = threadIdx.x & 3;
#pragma unroll
        for (int e = 0; e < 4; ++e) {
            float4 v = *(const float4*)(u + ((size_t)b * TLEN + t) * INW + q * 16 + e * 4);
            *(float4*)&ulds[b][q * 16 + e * 4] = v;
        }
    }
    float wreg[INW];
#pragma unroll
    for (int q = 0; q < INW / 4; ++q) {
        float4 v = *(const float4*)(w_in_w + (size_t)j * INW + q * 4);
        wreg[q * 4 + 0] = v.x; wreg[q * 4 + 1] = v.y;
        wreg[q * 4 + 2] = v.z; wreg[q * 4 + 3] = v.w;
    }
    float bias = w_in_b[j];
    __syncthreads();
    for (int b = 0; b < BSZ; ++b) {
        float s = bias;
        // float4 reads of the shared row: same address across all threads ->
        // LDS broadcast (free); 16 ds_read_b128 instead of 64 ds_read_b32.
#pragma unroll
        for (int q = 0; q < INW / 4; ++q) {
            float4 uu = *(const float4*)&ulds[b][q * 4];
            s = fmaf(uu.x, wreg[q * 4 + 0], s);
            s = fmaf(uu.y, wreg[q * 4 + 1], s);
            s = fmaf(uu.z, wreg[q * 4 + 2], s);
            s = fmaf(uu.w, wreg[q * 4 + 3], s);
        }
        float nz = noise[((size_t)t * BSZ + b) * HID + j];
        pre[((size_t)t * HID + j) * BSZ + b] = NOISE_STD * nz + TAU * s;
    }
}

// ---------------------------------------------------------------------------
// persistent kernel — FROZEN at the fabric-latency floor (R8/R9 verified):
//  - W fragments loaded directly from W[j] fp32 in the prologue (R9)
//  - R0 flag protocol; waves 0&1 dual-compute xn; wave1 publishes, wave0
//    stores trajWS (parallel ack-chains, R8)
//  - swapped-MFMA epilogue + whh-in-acc + transposed redw + fast_tanh (R3/R7)
// ---------------------------------------------------------------------------
__global__ __launch_bounds__(256, 1) void persist_kernel(
    const float* __restrict__ W,              // [HID][HID][HID] fp32
    const float* __restrict__ w_hh,
    const float* __restrict__ u,              // fallbacks
    const float* __restrict__ w_in_w,
    const float* __restrict__ w_in_b,
    const float* __restrict__ noise,
    const float* __restrict__ x0,
    u64* __restrict__ buf0,                   // [16][256] packets (t even reads)
    u64* __restrict__ buf1,                   // (t odd reads)
    float* __restrict__ traj,                 // [B][T][HID] (fallback path)
    float* __restrict__ trajWS,               // [T][HID][B] (fast path)
    float* __restrict__ xfinal,
    int* __restrict__ ready,                  // 256 flags, 64B apart (zeroed)
    const float* __restrict__ pre,            // [T][HID][B] or unused
    int use_pre, int use_tws) {
    __shared__ short rlds[16384];             // 32 KB swizzled r
    __shared__ float redw[256];               // [b][w] transposed partials
    __shared__ float exl[2][64];              // extra handoff wave0 -> wave1

    const int tid  = threadIdx.x;
    const int j    = blockIdx.x;
    const int w    = tid >> 6;
    const int lane = tid & 63;
    const int quad = lane >> 4;
    const int col  = lane & 15;

    // ---- W fragments direct from W: wreg[kk*4+mt][e] =
    //      bf16(W[j][(w*4+mt)*16+col][kk*32+quad*8+e])  (swapped-MFMA A-op)
    short8 wreg[32];
    {
        const float* __restrict__ wsrc = W + (size_t)j * HID * HID;
#pragma unroll
        for (int kk = 0; kk < 8; ++kk)
#pragma unroll
            for (int mt = 0; mt < 4; ++mt) {
                const float* __restrict__ p =
                    wsrc + (size_t)((w * 4 + mt) * 16 + col) * HID + kk * 32 + quad * 8;
                float4 f0 = *(const float4*)p;
                float4 f1 = *(const float4*)(p + 4);
                short8 s;
                __hip_bfloat16 h;
                h = __float2bfloat16(f0.x); s[0] = *(short*)&h;
                h = __float2bfloat16(f0.y); s[1] = *(short*)&h;
                h = __float2bfloat16(f0.z); s[2] = *(short*)&h;
                h = __float2bfloat16(f0.w); s[3] = *(short*)&h;
                h = __float2bfloat16(f1.x); s[4] = *(short*)&h;
                h = __float2bfloat16(f1.y); s[5] = *(short*)&h;
                h = __float2bfloat16(f1.z); s[6] = *(short*)&h;
                h = __float2bfloat16(f1.w); s[7] = *(short*)&h;
                wreg[kk * 4 + mt] = s;
            }
    }
    // whh folded into MFMA acc init (verified R5-R9)
    float whh16[16];
#pragma unroll
    for (int mt = 0; mt < 4; ++mt)
#pragma unroll
        for (int rg = 0; rg < 4; ++rg)
            whh16[mt * 4 + rg] = w_hh[j * HID + (w * 4 + mt) * 16 + quad * 4 + rg];

    // state copy in waves 0 AND 1 (identical arithmetic keeps them in sync)
    float xb = 0.f;
    if (tid < 128) xb = x0[lane * HID + j];

#pragma unroll 1
    for (int t = 0; t < TLEN; ++t) {
        const u64* __restrict__ rcur = (t & 1) ? buf1 : buf0;
        u64* __restrict__ rnxt = (t & 1) ? buf0 : buf1;

        // ---- input term (wave0 only) + LDS handoff for wave1 ----
        float extra = 0.f;
        if (tid < BSZ) {
            if (use_pre) {
                extra = pre[((size_t)t * HID + j) * BSZ + tid];
            } else {
                float isum = w_in_b[j];
                const float4* __restrict__ urow =
                    (const float4*)(u + ((size_t)tid * TLEN + t) * INW);
                const float4* __restrict__ wrow = (const float4*)(w_in_w + (size_t)j * INW);
#pragma unroll
                for (int q = 0; q < INW / 4; ++q) {
                    float4 uu = urow[q], ww = wrow[q];
                    isum = fmaf(uu.x, ww.x, isum);
                    isum = fmaf(uu.y, ww.y, isum);
                    isum = fmaf(uu.z, ww.z, isum);
                    isum = fmaf(uu.w, ww.w, isum);
                }
                float nz = noise[((size_t)t * BSZ + tid) * HID + j];
                extra = NOISE_STD * nz + TAU * isum;
            }
            exl[t & 1][tid] = extra;           // visible to wave1 after barrier B
        }

        // ---- thread-local wait: flag tid guards exactly this thread's data ----
        if (t > 0) {
            while (__hip_atomic_load(ready + tid * 16, __ATOMIC_RELAXED,
                                     __HIP_MEMORY_SCOPE_AGENT) < t)
                __builtin_amdgcn_s_sleep(1);
            asm volatile("" ::: "memory");
        }

        // ---- load own column (producer tid's output), fill rlds ----
        {
            u64 v[16];
#pragma unroll
            for (int g = 0; g < 16; ++g)
                v[g] = __hip_atomic_load(rcur + g * 256 + tid, __ATOMIC_RELAXED,
                                         __HIP_MEMORY_SCOPE_AGENT);
#pragma unroll
            for (int g = 0; g < 16; ++g)
#pragma unroll
                for (int e = 0; e < 4; ++e)
                    rlds[ridx(4 * g + e, tid)] = (short)(v[g] >> (16 * e));
        }
        __syncthreads();                       // barrier B: rlds (+exl) complete

        // wave1's extra, read early so the ds_read hides under the GEMM
        float ex_w1 = 0.f;
        if (w == 1) ex_w1 = exl[t & 1][lane];

        // ---- GEMM (swapped): D[i,b] = w_hh[j,i] + sum_k W[j,i,k] r[b,k] ----
        floatx4 acc[4][4];                     // acc[mt=i-tile][nt=b-tile]
#pragma unroll
        for (int mt = 0; mt < 4; ++mt)
#pragma unroll
            for (int nt = 0; nt < 4; ++nt)
                acc[mt][nt] = (floatx4){whh16[mt * 4 + 0], whh16[mt * 4 + 1],
                                        whh16[mt * 4 + 2], whh16[mt * 4 + 3]};

#pragma unroll
        for (int kk = 0; kk < 8; ++kk) {
            short8 afrag[4];
#pragma unroll
            for (int nt = 0; nt < 4; ++nt)
                afrag[nt] = *(const short8*)&rlds[ridx(nt * 16 + col, kk * 32 + quad * 8)];
#pragma unroll
            for (int mt = 0; mt < 4; ++mt)
#pragma unroll
                for (int nt = 0; nt < 4; ++nt)
                    acc[mt][nt] = __builtin_amdgcn_mfma_f32_16x16x32_bf16(
                        wreg[kk * 4 + mt], afrag[nt], acc[mt][nt], 0, 0, 0);
        }

        // ---- epilogue: part[b] = sum_i r[b,i]*P'[i,b] ----
        float part[4];
#pragma unroll
        for (int nt = 0; nt < 4; ++nt) part[nt] = 0.f;
#pragma unroll
        for (int mt = 0; mt < 4; ++mt) {
            const int ib = (w * 4 + mt) * 16 + quad * 4;
#pragma unroll
            for (int nt = 0; nt < 4; ++nt) {
                const int b = nt * 16 + col;
                shortx4 r4 = *(const shortx4*)&rlds[ridx(b, ib)];
#pragma unroll
                for (int rg = 0; rg < 4; ++rg) {
                    short rs = r4[rg];
                    float rv = __bfloat162float(*(__hip_bfloat16*)&rs);
                    part[nt] = fmaf(rv, acc[mt][nt][rg], part[nt]);
                }
            }
        }
#pragma unroll
        for (int nt = 0; nt < 4; ++nt) {
            part[nt] += __shfl_xor(part[nt], 16, 64);
            part[nt] += __shfl_xor(part[nt], 32, 64);
        }
        // transposed partial store: redw[b*4 + w] -> one float4 read per b
        if (quad == 0) {
#pragma unroll
            for (int nt = 0; nt < 4; ++nt)
                redw[(nt * 16 + col) * 4 + w] = part[nt];
        }
        __syncthreads();                       // barrier C: redw complete

        // ---- waves 0 & 1: both compute xn (identical); split store duties ----
        if (w < 2) {
            const int b = lane;
            float4 r4 = *(const float4*)&redw[b * 4];      // one ds_read_b128
            float rec = (r4.x + r4.y) + (r4.z + r4.w);
            float ex = (w == 0) ? extra : ex_w1;
            float xn = xb + ex + TAU * (rec - xb);
            xb = xn;

            if (w == 1) {
                // -------- publisher wave --------
                if (t < TLEN - 1) {
                    __hip_bfloat16 h = __float2bfloat16(fast_tanh(xn));
                    int hs = (int)(*(unsigned short*)&h);
                    int src = 4 * (lane & 15);
                    u64 pv = (u64)(unsigned)__shfl(hs, src + 0, 64)
                           | ((u64)(unsigned)__shfl(hs, src + 1, 64) << 16)
                           | ((u64)(unsigned)__shfl(hs, src + 2, 64) << 32)
                           | ((u64)(unsigned)__shfl(hs, src + 3, 64) << 48);
                    if (lane < 16)
                        __hip_atomic_store(rnxt + (size_t)lane * 256 + j, pv,
                                           __ATOMIC_RELAXED, __HIP_MEMORY_SCOPE_AGENT);
                    asm volatile("s_waitcnt vmcnt(0)" ::: "memory");   // data drain
                    if (lane == 0)
                        __hip_atomic_store(ready + j * 16, t + 1, __ATOMIC_RELAXED,
                                           __HIP_MEMORY_SCOPE_AGENT);
                    // flag-ack drain overlapped with the remote-flag window
                    asm volatile("s_waitcnt vmcnt(0)" ::: "memory");
                }
            } else {
                // -------- trajectory wave --------
                if (use_tws) {
                    trajWS[((size_t)t * HID + j) * BSZ + b] = xn;      // 256B coalesced
                } else {
                    traj[((size_t)b * TLEN + t) * HID + j] = xn;
                    if (t == TLEN - 1) xfinal[b * HID + j] = xn;
                }
                // store-ack drain off the poll path (overlaps remote window)
                asm volatile("s_waitcnt vmcnt(0)" ::: "memory");
            }
        }
    }
}

// ---------------------------------------------------------------------------
// fused transpose + output (fast path). block = t.
// ---------------------------------------------------------------------------
__global__ __launch_bounds__(256) void fixup_kernel(
    const float* __restrict__ trajWS,   // [T][HID][B]
    const float* __restrict__ w_out_w,  // [OUT][HID]
    const float* __restrict__ w_out_b,  // [OUT]
    float* __restrict__ traj,           // [B][T][HID]
    float* __restrict__ xfinal,         // [B][HID]
    float* __restrict__ out) {          // [B][T][OUT]
    __shared__ float xv[BSZ * 257];
    __shared__ float wol[OUTW * 257];
    const int t = blockIdx.x, tid = threadIdx.x;

#pragma unroll
    for (int it = 0; it < 16; ++it) {
        int flat = it * 1024 + tid * 4;          // j*64 + b
        float4 v = *(const float4*)(trajWS + (size_t)t * 16384 + flat);
        int jj = flat >> 6, b = flat & 63;
        xv[(b + 0) * 257 + jj] = v.x;
        xv[(b + 1) * 257 + jj] = v.y;
        xv[(b + 2) * 257 + jj] = v.z;
        xv[(b + 3) * 257 + jj] = v.w;
    }
#pragma unroll
    for (int it = 0; it < 8; ++it) {
        int flat = it * 1024 + tid * 4;          // o*256 + h
        float4 v = *(const float4*)(w_out_w + flat);
        int o = flat >> 8, h = flat & 255;
        *(float4*)&wol[o * 257 + h] = v;
    }
    __syncthreads();

    for (int b = 0; b < BSZ; ++b)
        traj[((size_t)b * TLEN + t) * HID + tid] = xv[b * 257 + tid];
    if (t == TLEN - 1)
        for (int b = 0; b < BSZ; ++b)
            xfinal[b * HID + tid] = xv[b * 257 + tid];

    __syncthreads();
#pragma unroll
    for (int it = 0; it < 64; ++it)
        xv[it * 257 + tid] = fast_tanh(xv[it * 257 + tid]);
    __syncthreads();

    const int o = tid & 31;
    const float bias = w_out_b[o];
#pragma unroll 1
    for (int rep = 0; rep < 8; ++rep) {
        int b = rep * 8 + (tid >> 5);
        float s = bias;
#pragma unroll 8
        for (int h = 0; h < HID; ++h)
            s = fmaf(xv[b * 257 + h], wol[o * 257 + h], s);
        out[((size_t)b * TLEN + t) * OUTW + o] = s;
    }
}

// ---------------------------------------------------------------------------
// fallback output kernel — used when ws too small
// ---------------------------------------------------------------------------
__global__ __launch_bounds__(256) void output_kernel(
    const float* __restrict__ traj, const float* __restrict__ w_out_w,
    const float* __restrict__ w_out_b, float* __restrict__ out) {
    __shared__ float th[8][HID + 1];
    const int bt0 = blockIdx.x * 8;
    const int tid = threadIdx.x;
#pragma unroll
    for (int m = 0; m < 8; ++m) {
        int idx = m * 256 + tid;
        th[idx >> 8][idx & 255] = fast_tanh(traj[(size_t)bt0 * HID + idx]);
    }
    __syncthreads();
    const int row = tid >> 5, o = tid & 31;
    const float* __restrict__ wrow = w_out_w + (size_t)o * HID;
    float s = w_out_b[o];
#pragma unroll 8
    for (int h = 0; h < HID; ++h) s = fmaf(th[row][h], wrow[h], s);
    out[(size_t)(bt0 + row) * OUTW + o] = s;
}

// ---------------------------------------------------------------------------
extern "C" void kernel_launch(void* const* d_in, const int* in_sizes, int n_in,
                              void* d_out, int out_size, void* d_ws, size_t ws_size,
                              hipStream_t stream) {
    const float* u       = (const float*)d_in[0];
    const float* x0      = (const float*)d_in[1];
    const float* noise   = (const float*)d_in[2];
    const float* w_hh    = (const float*)d_in[3];
    const float* W       = (const float*)d_in[4];
    const float* w_in_w  = (const float*)d_in[5];
    const float* w_in_b  = (const float*)d_in[6];
    const float* w_out_w = (const float*)d_in[7];
    const float* w_out_b = (const float*)d_in[8];

    float* out    = (float*)d_out;                     // [B][T][OUT]
    float* xfinal = out + (size_t)BSZ * TLEN * OUTW;
    float* traj   = xfinal + (size_t)BSZ * HID;

    // ws layout: buf0 32K | buf1 32K | flags 16K | trajWS 16.7M | pre 16.7M
    char* ws = (char*)d_ws;
    u64*   buf0 = (u64*)ws;
    u64*   buf1 = (u64*)(ws + 32768);
    int*   rdy  = (int*)(ws + 65536);
    float* tws  = (float*)(ws + 81920);
    float* pre  = (float*)(ws + 16859136);
    const size_t NEED_TWS = 16859136ull;
    const size_t NEED_PRE = 33636352ull;
    const int use_tws = (ws_size >= NEED_TWS) ? 1 : 0;
    const int use_pre = (ws_size >= NEED_PRE) ? 1 : 0;

    if (use_pre)
        pre_kernel<<<TLEN, 256, 0, stream>>>(u, w_in_w, w_in_b, noise, pre,
                                             x0, buf0, rdy);
    else
        init_kernel<<<16, 256, 0, stream>>>(x0, buf0, rdy);

    persist_kernel<<<256, 256, 0, stream>>>(
        W, w_hh, u, w_in_w, w_in_b, noise, x0,
        buf0, buf1, traj, tws, xfinal, rdy, pre, use_pre, use_tws);

    if (use_tws)
        fixup_kernel<<<TLEN, 256, 0, stream>>>(tws, w_out_w, w_out_b, traj, xfinal, out);
    else
        output_kernel<<<(BSZ * TLEN) / 8, 256, 0, stream>>>(traj, w_out_w, w_out_b, out);
}